// Round 15
// baseline (355.940 us; speedup 1.0000x reference)
//
#include <hip/hip_runtime.h>
#include <hip/hip_fp16.h>
#include <math.h>

// ---------------------------------------------------------------------------
// GATEncoder: 2x (GATConv(H=2,C=128) + exact GELU) + final projection.
// Carriers: fp16. GEMMs: 2-pass fp16 MFMA (B split hi/lo = exact to 2^-22),
//   BM=128 x BN=N, 512 thr / 8 waves. Staging via global_load_lds (width 16,
//   wave-linear LDS slots); L0's A cvt-staged manually. fp16 C written via
//   LDS-coalesced epilogue (kills 2x write amplification seen in r7 profile).
//   L0 epilogue fuses the layer-0 attention matvec (output-basis table).
// Gather: dual-edge wave layout + fused no-max softmax + head-mean+bias+GELU
//   + next-layer matvec (plateaued at ~80us: random-row fetch bound).
// CSR: hist -> hierarchical Hillis-Steele scan -> scatter via pcur atomic.
// ---------------------------------------------------------------------------

#define NEG_SLOPE 0.2f

typedef __attribute__((ext_vector_type(8))) _Float16 f16x8;
typedef __attribute__((ext_vector_type(8))) ushort u16x8;
typedef __attribute__((ext_vector_type(4))) float f32x4;

__device__ __forceinline__ ushort f32_to_f16u(float x)
{
    return __half_as_ushort(__float2half(x));   // RNE
}

__device__ __forceinline__ float f16u_to_f32(ushort u)
{
    return __half2float(__ushort_as_half(u));
}

__device__ __forceinline__ void split_f16(float x, ushort& h, ushort& l)
{
    const __half hh = __float2half(x);
    h = __half_as_ushort(hh);
    l = __half_as_ushort(__float2half(x - __half2float(hh)));
}

__device__ __forceinline__ float lrelu(float x)
{
    return x > 0.f ? x : NEG_SLOPE * x;
}

__device__ __forceinline__ float gelu_exact(float x)
{
    return 0.5f * x * (1.0f + erff(x * 0.7071067811865476f));
}

// async global->LDS, 16B per lane; LDS dest = wave-uniform base + lane*16
__device__ __forceinline__ void gload_lds16(const void* g, void* l)
{
    __builtin_amdgcn_global_load_lds(
        (const __attribute__((address_space(1))) void*)g,
        (__attribute__((address_space(3))) void*)l, 16, 0, 0);
}

// ---- fused prep: W splits + wt1 reduction + wtd0 direct + cnt zeroing -----
// blocks [0,448): split; [448,576): wt1 (W1@att1); 576: wtd0; [577,..): cnt=0
__global__ __launch_bounds__(256)
void prep_kernel(const float* __restrict__ W0, const float* __restrict__ W1,
                 const float* __restrict__ PW,
                 const float* __restrict__ as0, const float* __restrict__ ad0,
                 const float* __restrict__ as1, const float* __restrict__ ad1,
                 ushort* __restrict__ w0h, ushort* __restrict__ w0l,
                 ushort* __restrict__ w1h, ushort* __restrict__ w1l,
                 ushort* __restrict__ pwh, ushort* __restrict__ pwl,
                 float* __restrict__ wtd0, float* __restrict__ wt1,
                 int* __restrict__ cnt, int N)
{
    const int blk = blockIdx.x;
    if (blk >= 577) {
        int t2 = (blk - 577) * 256 + threadIdx.x;
        if (t2 < N) cnt[t2] = 0;
        return;
    }
    if (blk == 576) {
        const int col = threadIdx.x;
        float4 o;
        if (col < 128) o = make_float4(as0[col], 0.f, ad0[col], 0.f);
        else           o = make_float4(0.f, as0[col], 0.f, ad0[col]);
        *(float4*)(wtd0 + col * 4) = o;
        return;
    }
    if (blk < 448) {
        int t = blk * 256 + threadIdx.x;
        ushort h, l;
        if (t < 65536) {                        // W0: [256][256] -> [N][K]
            int k = t >> 8, n = t & 255;
            split_f16(W0[t], h, l);
            w0h[n * 256 + k] = h; w0l[n * 256 + k] = l;
        } else if (t < 65536 + 32768) {         // W1: [128][256] -> [N][K=128]
            int u = t - 65536;
            int k = u >> 8, n = u & 255;
            split_f16(W1[u], h, l);
            w1h[n * 128 + k] = h; w1l[n * 128 + k] = l;
        } else {                                // PW: [128][128] -> [N][K]
            int u = t - 65536 - 32768;
            int k = u >> 7, n = u & 127;
            split_f16(PW[u], h, l);
            pwh[n * 128 + k] = h; pwl[n * 128 + k] = l;
        }
        return;
    }
    // wt1 path: wt1[k][4] = {W1@att_s1 h0,h1, W1@att_d1 h0,h1}, k in [0,128)
    const int k = blk - 448;
    const int t = threadIdx.x;
    const int h = t >> 7, c = t & 127;
    const int lane = t & 63, wid = t >> 6;
    const float w = W1[(size_t)k * 256 + h * 128 + c];
    float ps = w * as1[h * 128 + c];
    float pd = w * ad1[h * 128 + c];
#pragma unroll
    for (int off = 1; off < 64; off <<= 1) {
        ps += __shfl_xor(ps, off, 64);
        pd += __shfl_xor(pd, off, 64);
    }
    __shared__ float sm[4][2];
    if (lane == 0) { sm[wid][0] = ps; sm[wid][1] = pd; }
    __syncthreads();
    if (t == 0) {
        wt1[k * 4 + 0] = sm[0][0] + sm[1][0];
        wt1[k * 4 + 1] = sm[2][0] + sm[3][0];
        wt1[k * 4 + 2] = sm[0][1] + sm[1][1];
        wt1[k * 4 + 3] = sm[2][1] + sm[3][1];
    }
}

// ---------------- 2-pass fp16 MFMA GEMM: 8 waves, BM=128, BN=N -------------
// SPLITA: A fp32 (cvt-staged); else A fp16 (global_load_lds, rows clamped).
// B hi/lo fp16 staged via global_load_lds. fp16 C via LDS-coalesced epilogue.
template<int BN, bool SPLITA>
__global__ __launch_bounds__(512)
void mfma_gemm3(const float* __restrict__ Af,
                const ushort* __restrict__ A16,
                const ushort* __restrict__ Bth, const ushort* __restrict__ Btl,
                const float* __restrict__ bias,
                float* __restrict__ Cf, ushort* __restrict__ Cb,
                const float* __restrict__ watt,
                float* __restrict__ a_sc, float* __restrict__ a_dc,
                int M, int K)
{
    constexpr int NF = BN / 64;          // 16x16 col-frags per wave
    constexpr int ASZ = 4096;            // A: [4 planes][128 rows][8] ushorts
    constexpr int BSZ = BN * 32;         // each B buffer: [4][BN][8] ushorts
    __shared__ ushort smem[ASZ + 2 * BSZ];
    ushort* Ah = smem;
    ushort* Bh = smem + ASZ;
    ushort* Bl = smem + ASZ + BSZ;

    const int tid = threadIdx.x;
    const int r0 = blockIdx.x * 128;
    const int w = tid >> 6, lane = tid & 63;
    const int wr = (w & 1) * 64;
    const int wc = (w >> 1) * (BN / 4);
    const int lr = lane & 15, kb = lane >> 4;

    // A slot (wave-linear for global_load_lds): s = tid -> plane s>>7, row s&127
    const int a_apl = tid >> 7, a_row = tid & 127;
    const int ca_row = min(r0 + a_row, M - 1);   // clamp: OOB rows' C never stored
    // manual (SPLITA) mapping
    const int arow_m = tid >> 2, apl_m = tid & 3;

    f32x4 acc[4][NF] = {};

    for (int kk = 0; kk < K; kk += 32) {
        // ---- stage A (128 x 32 fp16) ----
        if constexpr (SPLITA) {
            const int row = r0 + arow_m;
            u16x8 h0 = {};
            if (row < M) {
                const float* p = Af + (size_t)row * K + kk + apl_m * 8;
                float4 v0 = *(const float4*)(p);
                float4 v1 = *(const float4*)(p + 4);
                h0[0] = f32_to_f16u(v0.x); h0[1] = f32_to_f16u(v0.y);
                h0[2] = f32_to_f16u(v0.z); h0[3] = f32_to_f16u(v0.w);
                h0[4] = f32_to_f16u(v1.x); h0[5] = f32_to_f16u(v1.y);
                h0[6] = f32_to_f16u(v1.z); h0[7] = f32_to_f16u(v1.w);
            }
            *(u16x8*)&Ah[(apl_m * 128 + arow_m) * 8] = h0;
        } else {
            gload_lds16(A16 + (size_t)ca_row * K + kk + a_apl * 8,
                        &Ah[(size_t)(w * 64) * 8]);
        }
        // ---- stage B (BN x 32, hi+lo) via global_load_lds ----
#pragma unroll
        for (int q = 0; q < (4 * BN) / 512; ++q) {
            const int s = tid + q * 512;
            const int pl = s / BN, col = s % BN;
            const size_t goff = (size_t)col * K + kk + pl * 8;
            const size_t lbase = (size_t)(w * 64 + q * 512) * 8;
            gload_lds16(Bth + goff, &Bh[lbase]);
            gload_lds16(Btl + goff, &Bl[lbase]);
        }
        __syncthreads();

        f16x8 ah[4];
#pragma unroll
        for (int m = 0; m < 4; ++m)
            ah[m] = *(const f16x8*)&Ah[(kb * 128 + wr + m * 16 + lr) * 8];
#pragma unroll
        for (int n = 0; n < NF; ++n) {
            const f16x8 bh = *(const f16x8*)&Bh[(kb * BN + wc + n * 16 + lr) * 8];
            const f16x8 bl = *(const f16x8*)&Bl[(kb * BN + wc + n * 16 + lr) * 8];
#pragma unroll
            for (int m = 0; m < 4; ++m) {
                acc[m][n] = __builtin_amdgcn_mfma_f32_16x16x32_f16(ah[m], bh, acc[m][n], 0, 0, 0);
                acc[m][n] = __builtin_amdgcn_mfma_f32_16x16x32_f16(ah[m], bl, acc[m][n], 0, 0, 0);
            }
        }
        __syncthreads();
    }

    // ---- C write ----
    if (Cb) {
        // LDS-coalesced fp16 epilogue: two 64-row chunks of [64][BN] fp16.
#pragma unroll
        for (int c = 0; c < 2; ++c) {
            if (wr == c * 64) {
#pragma unroll
                for (int n = 0; n < NF; ++n) {
                    const int col = wc + n * 16 + lr;
#pragma unroll
                    for (int m = 0; m < 4; ++m) {
                        const int rl = m * 16 + kb * 4;
#pragma unroll
                        for (int j = 0; j < 4; ++j)
                            smem[(rl + j) * BN + col] = f32_to_f16u(acc[m][n][j]);
                    }
                }
            }
            __syncthreads();
#pragma unroll
            for (int q = 0; q < BN / 64; ++q) {
                const int slot = tid + q * 512;          // u16x8 units
                const int row = c * 64 + (slot * 8) / BN;
                const int colb = (slot * 8) % BN;
                const int grow = r0 + row;
                if (grow < M)
                    *(u16x8*)(Cb + (size_t)grow * BN + colb) = *(const u16x8*)&smem[slot * 8];
            }
            __syncthreads();
        }
    }
    if (Cf) {
#pragma unroll
        for (int n = 0; n < NF; ++n) {
            const int col = wc + n * 16 + lr;
            const float bv = bias ? bias[col] : 0.f;
#pragma unroll
            for (int m = 0; m < 4; ++m) {
                const int rowb = r0 + wr + m * 16 + kb * 4;
#pragma unroll
                for (int j = 0; j < 4; ++j) {
                    const int row = rowb + j;
                    if (row < M) Cf[(size_t)row * BN + col] = acc[m][n][j] + bv;
                }
            }
        }
    }

    // ---- fused score matvec: a_s/a_d[row] = C_row . watt (output basis) ----
    if (watt) {
        float* sp = (float*)smem;   // 8 KB scratch ([4 colwaves][128][4] f32)
        float4 wv[NF];
#pragma unroll
        for (int n = 0; n < NF; ++n)
            wv[n] = *(const float4*)(watt + (wc + n * 16 + lr) * 4);
#pragma unroll
        for (int m = 0; m < 4; ++m) {
#pragma unroll
            for (int j = 0; j < 4; ++j) {
                float s0 = 0.f, s1 = 0.f, s2 = 0.f, s3 = 0.f;
#pragma unroll
                for (int n = 0; n < NF; ++n) {
                    const float v = acc[m][n][j];
                    s0 += v * wv[n].x;
                    s1 += v * wv[n].y;
                    s2 += v * wv[n].z;
                    s3 += v * wv[n].w;
                }
#pragma unroll
                for (int off = 1; off < 16; off <<= 1) {
                    s0 += __shfl_xor(s0, off, 64);
                    s1 += __shfl_xor(s1, off, 64);
                    s2 += __shfl_xor(s2, off, 64);
                    s3 += __shfl_xor(s3, off, 64);
                }
                if (lr == 0) {
                    const int row = wr + m * 16 + kb * 4 + j;
                    float* d = sp + ((w >> 1) * 128 + row) * 4;
                    d[0] = s0; d[1] = s1; d[2] = s2; d[3] = s3;
                }
            }
        }
        __syncthreads();
        const int row = tid >> 2, comp = tid & 3;
        const float s = sp[(0 * 128 + row) * 4 + comp]
                      + sp[(1 * 128 + row) * 4 + comp]
                      + sp[(2 * 128 + row) * 4 + comp]
                      + sp[(3 * 128 + row) * 4 + comp];
        const int gr = r0 + row;
        if (gr < M) {
            if (comp < 2) a_sc[(size_t)gr * 2 + comp] = s;
            else          a_dc[(size_t)gr * 2 + (comp - 2)] = s;
        }
    }
}

// --------- fused gather: dual-edge layout + no-max softmax + epilogue ------
__global__ __launch_bounds__(256)
void gat_gather_kernel(const ushort* __restrict__ xlb,  // [n][256] fp16
                       const int* __restrict__ rowptr,
                       const int* __restrict__ esrc,
                       const float* __restrict__ a_si,
                       const float* __restrict__ a_di,
                       const float* __restrict__ bias,
                       const float* __restrict__ watt,  // nullable [128][4]
                       float* __restrict__ a_so, float* __restrict__ a_do,
                       ushort* __restrict__ outh,       // [n][128] fp16
                       int n)
{
    const int wave = threadIdx.x >> 6;
    const int lane = threadIdx.x & 63;
    const int v = blockIdx.x * 4 + wave;
    if (v >= n) return;
    const int half = lane >> 5;          // which edge of the pair
    const int il = lane & 31;            // channel-lane
    const int ch8 = il << 3;             // channels ch8..ch8+7
    const int hsel = il >> 4;            // head of my channel block

    const float2 advv = *(const float2*)(a_di + (size_t)v * 2);
    const float2 asvv = *(const float2*)(a_si + (size_t)v * 2);
    const float wself0 = __expf(lrelu(asvv.x + advv.x));
    const float wself1 = __expf(lrelu(asvv.y + advv.y));
    const float wselfh = hsel ? wself1 : wself0;

    const u16x8 xv = *(const u16x8*)(xlb + (size_t)v * 256 + ch8);
    float acc[8];
#pragma unroll
    for (int k = 0; k < 8; ++k)
        acc[k] = (half == 0) ? wselfh * f16u_to_f32(xv[k]) : 0.f;

    float ssum0 = (il == 0) ? wself0 : 0.f;   // per-half; halves replicate
    float ssum1 = (il == 0) ? wself1 : 0.f;

    const int beg = rowptr[v], end = rowptr[v + 1];
    for (int i = beg; i < end; i += 32) {
        const int cnt = min(32, end - i);
        int myidx = 0;
        float myw0 = 0.f, myw1 = 0.f;
        if (il < cnt) {
            myidx = esrc[i + il];
            const float2 e = *(const float2*)(a_si + (size_t)myidx * 2);
            myw0 = __expf(lrelu(e.x + advv.x));
            myw1 = __expf(lrelu(e.y + advv.y));
        }
        ssum0 += myw0;
        ssum1 += myw1;
#pragma unroll 2
        for (int j = 0; j < cnt; j += 2) {
            const int jj = j + half;                    // my half's edge
            const int src = __shfl(myidx, jj, 32);
            const float w0 = __shfl(myw0, jj, 32);
            const float w1 = __shfl(myw1, jj, 32);
            const float wgt = hsel ? w1 : w0;           // 0 when jj==cnt (odd tail)
            const u16x8 xs = *(const u16x8*)(xlb + (size_t)src * 256 + ch8);
#pragma unroll
            for (int k = 0; k < 8; ++k)
                acc[k] += wgt * f16u_to_f32(xs[k]);
        }
    }

    // denominators: reduce within each half (offsets <= 16 stay in-half)
#pragma unroll
    for (int off = 1; off <= 16; off <<= 1) {
        ssum0 += __shfl_xor(ssum0, off, 64);
        ssum1 += __shfl_xor(ssum1, off, 64);
    }
    const float inv = 1.0f / ((hsel ? ssum1 : ssum0) + 1e-16f);

    // combine edge-streams, normalize, head-mean (ch <-> ch+128)
    float o[8];
#pragma unroll
    for (int k = 0; k < 8; ++k) {
        float a = acc[k] + __shfl_xor(acc[k], 32, 64);
        a *= inv;
        o[k] = 0.5f * (a + __shfl_xor(a, 16, 64));
    }

    if (il < 16) {   // lanes holding final channels 0..127 (both halves)
        const float4 bb0 = *(const float4*)(bias + ch8);
        const float4 bb1 = *(const float4*)(bias + ch8 + 4);
        o[0] = gelu_exact(o[0] + bb0.x);
        o[1] = gelu_exact(o[1] + bb0.y);
        o[2] = gelu_exact(o[2] + bb0.z);
        o[3] = gelu_exact(o[3] + bb0.w);
        o[4] = gelu_exact(o[4] + bb1.x);
        o[5] = gelu_exact(o[5] + bb1.y);
        o[6] = gelu_exact(o[6] + bb1.z);
        o[7] = gelu_exact(o[7] + bb1.w);

        if (watt) {
            float s0 = 0.f, s1 = 0.f, d0 = 0.f, d1 = 0.f;
#pragma unroll
            for (int k = 0; k < 8; ++k) {
                const float4 wv = *(const float4*)(watt + (ch8 + k) * 4);
                s0 += o[k] * wv.x;
                s1 += o[k] * wv.y;
                d0 += o[k] * wv.z;
                d1 += o[k] * wv.w;
            }
#pragma unroll
            for (int off = 1; off <= 8; off <<= 1) {
                s0 += __shfl_xor(s0, off, 64);
                s1 += __shfl_xor(s1, off, 64);
                d0 += __shfl_xor(d0, off, 64);
                d1 += __shfl_xor(d1, off, 64);
            }
            if (lane == 0) {
                *(float2*)(a_so + (size_t)v * 2) = make_float2(s0, s1);
                *(float2*)(a_do + (size_t)v * 2) = make_float2(d0, d1);
            }
        }

        if (half == 0) {
            u16x8 st;
#pragma unroll
            for (int k = 0; k < 8; ++k) st[k] = f32_to_f16u(o[k]);
            *(u16x8*)(outh + (size_t)v * 128 + ch8) = st;
        }
    }
}

// ---------------------- CSR build (by dst) ---------------------------------
__global__ __launch_bounds__(256)
void hist_kernel(const int* __restrict__ ei, int* __restrict__ cnt, int E)
{
    int e = blockIdx.x * 256 + threadIdx.x;
    if (e < E) atomicAdd(&cnt[ei[E + e]], 1);
}

__global__ __launch_bounds__(256)
void blocksum_kernel(const int* __restrict__ cnt, int* __restrict__ bsum, int n)
{
    __shared__ int sm[256];
    const int t = threadIdx.x;
    const int i = blockIdx.x * 256 + t;
    sm[t] = (i < n) ? cnt[i] : 0;
    __syncthreads();
#pragma unroll
    for (int off = 1; off < 256; off <<= 1) {
        int u = (t >= off) ? sm[t - off] : 0;
        __syncthreads();
        sm[t] += u;
        __syncthreads();
    }
    if (t == 255) bsum[blockIdx.x] = sm[255];
}

__global__ __launch_bounds__(256)
void scan_bsum_kernel(int* __restrict__ bsum, int nb, int* __restrict__ ptr, int n)
{
    __shared__ int sm[256];
    const int t = threadIdx.x;
    const int v = (t < nb) ? bsum[t] : 0;
    sm[t] = v;
    __syncthreads();
#pragma unroll
    for (int off = 1; off < 256; off <<= 1) {
        int u = (t >= off) ? sm[t - off] : 0;
        __syncthreads();
        sm[t] += u;
        __syncthreads();
    }
    if (t < nb) bsum[t] = sm[t] - v;
    if (t == 255) ptr[n] = sm[255];
}

__global__ __launch_bounds__(256)
void scan_out_kernel(const int* __restrict__ cnt, const int* __restrict__ bsum,
                     int* __restrict__ ptr, int* __restrict__ pcur, int n)
{
    __shared__ int sm[256];
    const int t = threadIdx.x;
    const int i = blockIdx.x * 256 + t;
    const int v = (i < n) ? cnt[i] : 0;
    sm[t] = v;
    __syncthreads();
#pragma unroll
    for (int off = 1; off < 256; off <<= 1) {
        int u = (t >= off) ? sm[t - off] : 0;
        __syncthreads();
        sm[t] += u;
        __syncthreads();
    }
    if (i < n) {
        const int val = bsum[blockIdx.x] + sm[t] - v;
        ptr[i] = val;
        pcur[i] = val;
    }
}

__global__ __launch_bounds__(256)
void scatter_kernel(const int* __restrict__ ei, int* __restrict__ pcur,
                    int* __restrict__ esrc, int E)
{
    int e = blockIdx.x * 256 + threadIdx.x;
    if (e < E) {
        int dst = ei[E + e];
        int src = ei[e];
        int pos = atomicAdd(&pcur[dst], 1);
        esrc[pos] = src;
    }
}

// ---------------------------------------------------------------------------
extern "C" void kernel_launch(void* const* d_in, const int* in_sizes, int n_in,
                              void* d_out, int out_size, void* d_ws, size_t ws_size,
                              hipStream_t stream)
{
    const float* x       = (const float*)d_in[0];
    const int*   ei      = (const int*)d_in[1];
    const float* W0      = (const float*)d_in[2];
    const float* att_s0  = (const float*)d_in[3];
    const float* att_d0  = (const float*)d_in[4];
    const float* b0      = (const float*)d_in[5];
    const float* W1      = (const float*)d_in[6];
    const float* att_s1  = (const float*)d_in[7];
    const float* att_d1  = (const float*)d_in[8];
    const float* b1      = (const float*)d_in[9];
    const float* pw      = (const float*)d_in[10];
    const float* pb      = (const float*)d_in[11];

    const int N = in_sizes[0] / 256;   // 50000
    const int E = in_sizes[1] / 2;     // 800000
    const int NB = (N + 255) / 256;    // scan blocks (<=256)

    // workspace layout
    ushort* xlb  = (ushort*)d_ws;                    // N*256 fp16
    ushort* hbuf = xlb + (size_t)N * 256;            // N*128 fp16
    float*  a_s  = (float*)(hbuf + (size_t)N * 128); // N*2  (layer-0 scores)
    float*  a_d  = a_s + (size_t)N * 2;              // N*2
    float*  a_s2 = a_d + (size_t)N * 2;              // N*2  (layer-1 scores)
    float*  a_d2 = a_s2 + (size_t)N * 2;             // N*2
    float*  wtd0 = a_d2 + (size_t)N * 2;             // 256*4 (direct basis)
    float*  wt1  = wtd0 + 256 * 4;                   // 128*4
    int*    cnt  = (int*)(wt1 + 128 * 4);            // N
    int*    ptr  = cnt + N;                          // N+1
    int*    pcur = ptr + (N + 1);                    // N
    int*    bsm  = pcur + N;                         // 256
    int*    esr  = bsm + 256;                        // E
    ushort* w0h  = (ushort*)(esr + E);               // 256*256
    ushort* w0l  = w0h + 256 * 256;
    ushort* w1h  = w0l + 256 * 256;                  // 256*128
    ushort* w1l  = w1h + 256 * 128;
    ushort* pwh  = w1l + 256 * 128;                  // 128*128
    ushort* pwl  = pwh + 128 * 128;

    const int ablk = (N + 3) / 4;
    const int eblk = (E + 255) / 256;
    const int gblk = (N + 127) / 128;   // 391 GEMM row-blocks

    // ---- fused prep: splits + wt1 + wtd0 + cnt zeroing ----
    prep_kernel<<<577 + NB, 256, 0, stream>>>(
        W0, W1, pw, att_s0, att_d0, att_s1, att_d1,
        w0h, w0l, w1h, w1l, pwh, pwl, wtd0, wt1, cnt, N);

    // ---- CSR build ----
    hist_kernel<<<eblk, 256, 0, stream>>>(ei, cnt, E);
    blocksum_kernel<<<NB, 256, 0, stream>>>(cnt, bsm, N);
    scan_bsum_kernel<<<1, 256, 0, stream>>>(bsm, NB, ptr, N);
    scan_out_kernel<<<NB, 256, 0, stream>>>(cnt, bsm, ptr, pcur, N);
    scatter_kernel<<<eblk, 256, 0, stream>>>(ei, pcur, esr, E);

    // ---- layer 0 (GEMM epilogue also emits layer-0 scores, direct basis) --
    mfma_gemm3<256, true><<<gblk, 512, 0, stream>>>(
        x, nullptr, w0h, w0l, nullptr, nullptr, xlb, wtd0, a_s, a_d, N, 256);
    gat_gather_kernel<<<ablk, 256, 0, stream>>>(
        xlb, ptr, esr, a_s, a_d, b0, wt1, a_s2, a_d2, hbuf, N);

    // ---- layer 1 (A = hbuf fp16, exact) ----
    mfma_gemm3<256, false><<<gblk, 512, 0, stream>>>(
        nullptr, hbuf, w1h, w1l, nullptr, nullptr, xlb, nullptr, nullptr, nullptr, N, 128);
    gat_gather_kernel<<<ablk, 256, 0, stream>>>(
        xlb, ptr, esr, a_s2, a_d2, b1, nullptr, nullptr, nullptr, hbuf, N);

    // ---- projection ----
    mfma_gemm3<128, false><<<gblk, 512, 0, stream>>>(
        nullptr, hbuf, pwh, pwl, pb, (float*)d_out, nullptr, nullptr, nullptr, nullptr, N, 128);
}

// Round 16
// 332.509 us; speedup vs baseline: 1.0705x; 1.0705x over previous
//
#include <hip/hip_runtime.h>
#include <hip/hip_fp16.h>
#include <math.h>

// ---------------------------------------------------------------------------
// GATEncoder: 2x (GATConv(H=2,C=128) + exact GELU) + final projection.
// Carriers: fp16. GEMMs: 2-pass fp16 MFMA (B split hi/lo = exact to 2^-22),
//   BM=128 x BN=N, 512 thr / 8 waves, round-14 vector-load staging (coalesced
//   64B/row groups). fp16 C via LDS-coalesced epilogue (fixes 2x write amp of
//   2B scalar stores). L0 epilogue fuses layer-0 attention matvec.
// Gather: dual-edge wave layout + fused no-max softmax + head-mean+bias+GELU
//   + next-layer matvec (plateaued ~80us: random-row fetch bound).
// CSR: hist -> hierarchical Hillis-Steele scan -> scatter via pcur atomic.
// ---------------------------------------------------------------------------

#define NEG_SLOPE 0.2f

typedef __attribute__((ext_vector_type(8))) _Float16 f16x8;
typedef __attribute__((ext_vector_type(8))) ushort u16x8;
typedef __attribute__((ext_vector_type(4))) float f32x4;

__device__ __forceinline__ ushort f32_to_f16u(float x)
{
    return __half_as_ushort(__float2half(x));   // RNE
}

__device__ __forceinline__ float f16u_to_f32(ushort u)
{
    return __half2float(__ushort_as_half(u));
}

__device__ __forceinline__ void split_f16(float x, ushort& h, ushort& l)
{
    const __half hh = __float2half(x);
    h = __half_as_ushort(hh);
    l = __half_as_ushort(__float2half(x - __half2float(hh)));
}

__device__ __forceinline__ float lrelu(float x)
{
    return x > 0.f ? x : NEG_SLOPE * x;
}

__device__ __forceinline__ float gelu_exact(float x)
{
    return 0.5f * x * (1.0f + erff(x * 0.7071067811865476f));
}

// ---- fused prep: W splits + wt1 reduction + wtd0 direct + cnt zeroing -----
// blocks [0,448): split; [448,576): wt1 (W1@att1); 576: wtd0; [577,..): cnt=0
__global__ __launch_bounds__(256)
void prep_kernel(const float* __restrict__ W0, const float* __restrict__ W1,
                 const float* __restrict__ PW,
                 const float* __restrict__ as0, const float* __restrict__ ad0,
                 const float* __restrict__ as1, const float* __restrict__ ad1,
                 ushort* __restrict__ w0h, ushort* __restrict__ w0l,
                 ushort* __restrict__ w1h, ushort* __restrict__ w1l,
                 ushort* __restrict__ pwh, ushort* __restrict__ pwl,
                 float* __restrict__ wtd0, float* __restrict__ wt1,
                 int* __restrict__ cnt, int N)
{
    const int blk = blockIdx.x;
    if (blk >= 577) {
        int t2 = (blk - 577) * 256 + threadIdx.x;
        if (t2 < N) cnt[t2] = 0;
        return;
    }
    if (blk == 576) {
        const int col = threadIdx.x;
        float4 o;
        if (col < 128) o = make_float4(as0[col], 0.f, ad0[col], 0.f);
        else           o = make_float4(0.f, as0[col], 0.f, ad0[col]);
        *(float4*)(wtd0 + col * 4) = o;
        return;
    }
    if (blk < 448) {
        int t = blk * 256 + threadIdx.x;
        ushort h, l;
        if (t < 65536) {                        // W0: [256][256] -> [N][K]
            int k = t >> 8, n = t & 255;
            split_f16(W0[t], h, l);
            w0h[n * 256 + k] = h; w0l[n * 256 + k] = l;
        } else if (t < 65536 + 32768) {         // W1: [128][256] -> [N][K=128]
            int u = t - 65536;
            int k = u >> 8, n = u & 255;
            split_f16(W1[u], h, l);
            w1h[n * 128 + k] = h; w1l[n * 128 + k] = l;
        } else {                                // PW: [128][128] -> [N][K]
            int u = t - 65536 - 32768;
            int k = u >> 7, n = u & 127;
            split_f16(PW[u], h, l);
            pwh[n * 128 + k] = h; pwl[n * 128 + k] = l;
        }
        return;
    }
    // wt1 path: wt1[k][4] = {W1@att_s1 h0,h1, W1@att_d1 h0,h1}, k in [0,128)
    const int k = blk - 448;
    const int t = threadIdx.x;
    const int h = t >> 7, c = t & 127;
    const int lane = t & 63, wid = t >> 6;
    const float w = W1[(size_t)k * 256 + h * 128 + c];
    float ps = w * as1[h * 128 + c];
    float pd = w * ad1[h * 128 + c];
#pragma unroll
    for (int off = 1; off < 64; off <<= 1) {
        ps += __shfl_xor(ps, off, 64);
        pd += __shfl_xor(pd, off, 64);
    }
    __shared__ float sm[4][2];
    if (lane == 0) { sm[wid][0] = ps; sm[wid][1] = pd; }
    __syncthreads();
    if (t == 0) {
        wt1[k * 4 + 0] = sm[0][0] + sm[1][0];
        wt1[k * 4 + 1] = sm[2][0] + sm[3][0];
        wt1[k * 4 + 2] = sm[0][1] + sm[1][1];
        wt1[k * 4 + 3] = sm[2][1] + sm[3][1];
    }
}

// ---------------- 2-pass fp16 MFMA GEMM: 8 waves, BM=128, BN=N -------------
// SPLITA: A fp32 (cvt-staged); else A fp16. Round-14 coalesced vector staging.
// fp16 C written via LDS-coalesced epilogue (full-wave 1KB stores).
template<int BN, bool SPLITA>
__global__ __launch_bounds__(512)
void mfma_gemm3(const float* __restrict__ Af,
                const ushort* __restrict__ A16,
                const ushort* __restrict__ Bth, const ushort* __restrict__ Btl,
                const float* __restrict__ bias,
                float* __restrict__ Cf, ushort* __restrict__ Cb,
                const float* __restrict__ watt,
                float* __restrict__ a_sc, float* __restrict__ a_dc,
                int M, int K)
{
    constexpr int NF = BN / 64;          // 16x16 col-frags per wave
    constexpr int ASZ = 4096;            // A: [4 planes][128 rows][8] ushorts
    constexpr int BSZ = BN * 32;         // B buf: [4][BN][8] ushorts
    __shared__ ushort smem[ASZ + 2 * BSZ];
    ushort* Ah = smem;
    ushort* Bh = smem + ASZ;
    ushort* Bl = smem + ASZ + BSZ;

    const int tid = threadIdx.x;
    const int r0 = blockIdx.x * 128;
    const int w = tid >> 6, lane = tid & 63;
    const int wr = (w & 1) * 64;
    const int wc = (w >> 1) * (BN / 4);
    const int lr = lane & 15, kb = lane >> 4;

    const int arow = tid >> 2;           // 0..127
    const int apl = tid & 3;             // k-plane (8-wide)

    f32x4 acc[4][NF] = {};

    for (int kk = 0; kk < K; kk += 32) {
        // ---- stage A (128 x 32, fp16; 4 lanes/row -> 64B contiguous) ----
        {
            const int row = r0 + arow;
            u16x8 h0 = {};
            if (row < M) {
                if constexpr (SPLITA) {
                    const float* p = Af + (size_t)row * K + kk + apl * 8;
                    float4 v0 = *(const float4*)(p);
                    float4 v1 = *(const float4*)(p + 4);
                    h0[0] = f32_to_f16u(v0.x); h0[1] = f32_to_f16u(v0.y);
                    h0[2] = f32_to_f16u(v0.z); h0[3] = f32_to_f16u(v0.w);
                    h0[4] = f32_to_f16u(v1.x); h0[5] = f32_to_f16u(v1.y);
                    h0[6] = f32_to_f16u(v1.z); h0[7] = f32_to_f16u(v1.w);
                } else {
                    h0 = *(const u16x8*)(A16 + (size_t)row * K + kk + apl * 8);
                }
            }
            *(u16x8*)&Ah[(apl * 128 + arow) * 8] = h0;
        }
        // ---- stage B (BN x 32, hi+lo) ----
        if constexpr (BN == 256) {
            const int col = tid >> 1, half = tid & 1;
            const ushort* ph = Bth + (size_t)col * K + kk + half * 16;
            const ushort* pl = Btl + (size_t)col * K + kk + half * 16;
            *(u16x8*)&Bh[((half * 2 + 0) * BN + col) * 8] = *(const u16x8*)(ph);
            *(u16x8*)&Bh[((half * 2 + 1) * BN + col) * 8] = *(const u16x8*)(ph + 8);
            *(u16x8*)&Bl[((half * 2 + 0) * BN + col) * 8] = *(const u16x8*)(pl);
            *(u16x8*)&Bl[((half * 2 + 1) * BN + col) * 8] = *(const u16x8*)(pl + 8);
        } else {
            const int col = tid >> 2, pl = tid & 3;
            *(u16x8*)&Bh[(pl * BN + col) * 8] = *(const u16x8*)(Bth + (size_t)col * K + kk + pl * 8);
            *(u16x8*)&Bl[(pl * BN + col) * 8] = *(const u16x8*)(Btl + (size_t)col * K + kk + pl * 8);
        }
        __syncthreads();

        f16x8 ah[4];
#pragma unroll
        for (int m = 0; m < 4; ++m)
            ah[m] = *(const f16x8*)&Ah[(kb * 128 + wr + m * 16 + lr) * 8];
#pragma unroll
        for (int n = 0; n < NF; ++n) {
            const f16x8 bh = *(const f16x8*)&Bh[(kb * BN + wc + n * 16 + lr) * 8];
            const f16x8 bl = *(const f16x8*)&Bl[(kb * BN + wc + n * 16 + lr) * 8];
#pragma unroll
            for (int m = 0; m < 4; ++m) {
                acc[m][n] = __builtin_amdgcn_mfma_f32_16x16x32_f16(ah[m], bh, acc[m][n], 0, 0, 0);
                acc[m][n] = __builtin_amdgcn_mfma_f32_16x16x32_f16(ah[m], bl, acc[m][n], 0, 0, 0);
            }
        }
        __syncthreads();
    }

    // ---- C write ----
    if (Cb) {
        // LDS-coalesced fp16 epilogue: two 64-row chunks of [64][BN] fp16.
#pragma unroll
        for (int c = 0; c < 2; ++c) {
            if (wr == c * 64) {
#pragma unroll
                for (int n = 0; n < NF; ++n) {
                    const int col = wc + n * 16 + lr;
#pragma unroll
                    for (int m = 0; m < 4; ++m) {
                        const int rl = m * 16 + kb * 4;
#pragma unroll
                        for (int j = 0; j < 4; ++j)
                            smem[(rl + j) * BN + col] = f32_to_f16u(acc[m][n][j]);
                    }
                }
            }
            __syncthreads();
#pragma unroll
            for (int q = 0; q < BN / 64; ++q) {
                const int slot = tid + q * 512;          // u16x8 units
                const int row = c * 64 + (slot * 8) / BN;
                const int colb = (slot * 8) % BN;
                const int grow = r0 + row;
                if (grow < M)
                    *(u16x8*)(Cb + (size_t)grow * BN + colb) = *(const u16x8*)&smem[slot * 8];
            }
            __syncthreads();
        }
    }
    if (Cf) {
#pragma unroll
        for (int n = 0; n < NF; ++n) {
            const int col = wc + n * 16 + lr;
            const float bv = bias ? bias[col] : 0.f;
#pragma unroll
            for (int m = 0; m < 4; ++m) {
                const int rowb = r0 + wr + m * 16 + kb * 4;
#pragma unroll
                for (int j = 0; j < 4; ++j) {
                    const int row = rowb + j;
                    if (row < M) Cf[(size_t)row * BN + col] = acc[m][n][j] + bv;
                }
            }
        }
    }

    // ---- fused score matvec: a_s/a_d[row] = C_row . watt (output basis) ----
    if (watt) {
        float* sp = (float*)smem;   // 8 KB scratch ([4 colwaves][128][4] f32)
        float4 wv[NF];
#pragma unroll
        for (int n = 0; n < NF; ++n)
            wv[n] = *(const float4*)(watt + (wc + n * 16 + lr) * 4);
#pragma unroll
        for (int m = 0; m < 4; ++m) {
#pragma unroll
            for (int j = 0; j < 4; ++j) {
                float s0 = 0.f, s1 = 0.f, s2 = 0.f, s3 = 0.f;
#pragma unroll
                for (int n = 0; n < NF; ++n) {
                    const float v = acc[m][n][j];
                    s0 += v * wv[n].x;
                    s1 += v * wv[n].y;
                    s2 += v * wv[n].z;
                    s3 += v * wv[n].w;
                }
#pragma unroll
                for (int off = 1; off < 16; off <<= 1) {
                    s0 += __shfl_xor(s0, off, 64);
                    s1 += __shfl_xor(s1, off, 64);
                    s2 += __shfl_xor(s2, off, 64);
                    s3 += __shfl_xor(s3, off, 64);
                }
                if (lr == 0) {
                    const int row = wr + m * 16 + kb * 4 + j;
                    float* d = sp + ((w >> 1) * 128 + row) * 4;
                    d[0] = s0; d[1] = s1; d[2] = s2; d[3] = s3;
                }
            }
        }
        __syncthreads();
        const int row = tid >> 2, comp = tid & 3;
        const float s = sp[(0 * 128 + row) * 4 + comp]
                      + sp[(1 * 128 + row) * 4 + comp]
                      + sp[(2 * 128 + row) * 4 + comp]
                      + sp[(3 * 128 + row) * 4 + comp];
        const int gr = r0 + row;
        if (gr < M) {
            if (comp < 2) a_sc[(size_t)gr * 2 + comp] = s;
            else          a_dc[(size_t)gr * 2 + (comp - 2)] = s;
        }
    }
}

// --------- fused gather: dual-edge layout + no-max softmax + epilogue ------
__global__ __launch_bounds__(256)
void gat_gather_kernel(const ushort* __restrict__ xlb,  // [n][256] fp16
                       const int* __restrict__ rowptr,
                       const int* __restrict__ esrc,
                       const float* __restrict__ a_si,
                       const float* __restrict__ a_di,
                       const float* __restrict__ bias,
                       const float* __restrict__ watt,  // nullable [128][4]
                       float* __restrict__ a_so, float* __restrict__ a_do,
                       ushort* __restrict__ outh,       // [n][128] fp16
                       int n)
{
    const int wave = threadIdx.x >> 6;
    const int lane = threadIdx.x & 63;
    const int v = blockIdx.x * 4 + wave;
    if (v >= n) return;
    const int half = lane >> 5;          // which edge of the pair
    const int il = lane & 31;            // channel-lane
    const int ch8 = il << 3;             // channels ch8..ch8+7
    const int hsel = il >> 4;            // head of my channel block

    const float2 advv = *(const float2*)(a_di + (size_t)v * 2);
    const float2 asvv = *(const float2*)(a_si + (size_t)v * 2);
    const float wself0 = __expf(lrelu(asvv.x + advv.x));
    const float wself1 = __expf(lrelu(asvv.y + advv.y));
    const float wselfh = hsel ? wself1 : wself0;

    const u16x8 xv = *(const u16x8*)(xlb + (size_t)v * 256 + ch8);
    float acc[8];
#pragma unroll
    for (int k = 0; k < 8; ++k)
        acc[k] = (half == 0) ? wselfh * f16u_to_f32(xv[k]) : 0.f;

    float ssum0 = (il == 0) ? wself0 : 0.f;   // per-half; halves replicate
    float ssum1 = (il == 0) ? wself1 : 0.f;

    const int beg = rowptr[v], end = rowptr[v + 1];
    for (int i = beg; i < end; i += 32) {
        const int cnt = min(32, end - i);
        int myidx = 0;
        float myw0 = 0.f, myw1 = 0.f;
        if (il < cnt) {
            myidx = esrc[i + il];
            const float2 e = *(const float2*)(a_si + (size_t)myidx * 2);
            myw0 = __expf(lrelu(e.x + advv.x));
            myw1 = __expf(lrelu(e.y + advv.y));
        }
        ssum0 += myw0;
        ssum1 += myw1;
#pragma unroll 2
        for (int j = 0; j < cnt; j += 2) {
            const int jj = j + half;                    // my half's edge
            const int src = __shfl(myidx, jj, 32);
            const float w0 = __shfl(myw0, jj, 32);
            const float w1 = __shfl(myw1, jj, 32);
            const float wgt = hsel ? w1 : w0;           // 0 when jj==cnt (odd tail)
            const u16x8 xs = *(const u16x8*)(xlb + (size_t)src * 256 + ch8);
#pragma unroll
            for (int k = 0; k < 8; ++k)
                acc[k] += wgt * f16u_to_f32(xs[k]);
        }
    }

    // denominators: reduce within each half (offsets <= 16 stay in-half)
#pragma unroll
    for (int off = 1; off <= 16; off <<= 1) {
        ssum0 += __shfl_xor(ssum0, off, 64);
        ssum1 += __shfl_xor(ssum1, off, 64);
    }
    const float inv = 1.0f / ((hsel ? ssum1 : ssum0) + 1e-16f);

    // combine edge-streams, normalize, head-mean (ch <-> ch+128)
    float o[8];
#pragma unroll
    for (int k = 0; k < 8; ++k) {
        float a = acc[k] + __shfl_xor(acc[k], 32, 64);
        a *= inv;
        o[k] = 0.5f * (a + __shfl_xor(a, 16, 64));
    }

    if (il < 16) {   // lanes holding final channels 0..127 (both halves)
        const float4 bb0 = *(const float4*)(bias + ch8);
        const float4 bb1 = *(const float4*)(bias + ch8 + 4);
        o[0] = gelu_exact(o[0] + bb0.x);
        o[1] = gelu_exact(o[1] + bb0.y);
        o[2] = gelu_exact(o[2] + bb0.z);
        o[3] = gelu_exact(o[3] + bb0.w);
        o[4] = gelu_exact(o[4] + bb1.x);
        o[5] = gelu_exact(o[5] + bb1.y);
        o[6] = gelu_exact(o[6] + bb1.z);
        o[7] = gelu_exact(o[7] + bb1.w);

        if (watt) {
            float s0 = 0.f, s1 = 0.f, d0 = 0.f, d1 = 0.f;
#pragma unroll
            for (int k = 0; k < 8; ++k) {
                const float4 wv = *(const float4*)(watt + (ch8 + k) * 4);
                s0 += o[k] * wv.x;
                s1 += o[k] * wv.y;
                d0 += o[k] * wv.z;
                d1 += o[k] * wv.w;
            }
#pragma unroll
            for (int off = 1; off <= 8; off <<= 1) {
                s0 += __shfl_xor(s0, off, 64);
                s1 += __shfl_xor(s1, off, 64);
                d0 += __shfl_xor(d0, off, 64);
                d1 += __shfl_xor(d1, off, 64);
            }
            if (lane == 0) {
                *(float2*)(a_so + (size_t)v * 2) = make_float2(s0, s1);
                *(float2*)(a_do + (size_t)v * 2) = make_float2(d0, d1);
            }
        }

        if (half == 0) {
            u16x8 st;
#pragma unroll
            for (int k = 0; k < 8; ++k) st[k] = f32_to_f16u(o[k]);
            *(u16x8*)(outh + (size_t)v * 128 + ch8) = st;
        }
    }
}

// ---------------------- CSR build (by dst) ---------------------------------
__global__ __launch_bounds__(256)
void hist_kernel(const int* __restrict__ ei, int* __restrict__ cnt, int E)
{
    int e = blockIdx.x * 256 + threadIdx.x;
    if (e < E) atomicAdd(&cnt[ei[E + e]], 1);
}

__global__ __launch_bounds__(256)
void blocksum_kernel(const int* __restrict__ cnt, int* __restrict__ bsum, int n)
{
    __shared__ int sm[256];
    const int t = threadIdx.x;
    const int i = blockIdx.x * 256 + t;
    sm[t] = (i < n) ? cnt[i] : 0;
    __syncthreads();
#pragma unroll
    for (int off = 1; off < 256; off <<= 1) {
        int u = (t >= off) ? sm[t - off] : 0;
        __syncthreads();
        sm[t] += u;
        __syncthreads();
    }
    if (t == 255) bsum[blockIdx.x] = sm[255];
}

__global__ __launch_bounds__(256)
void scan_bsum_kernel(int* __restrict__ bsum, int nb, int* __restrict__ ptr, int n)
{
    __shared__ int sm[256];
    const int t = threadIdx.x;
    const int v = (t < nb) ? bsum[t] : 0;
    sm[t] = v;
    __syncthreads();
#pragma unroll
    for (int off = 1; off < 256; off <<= 1) {
        int u = (t >= off) ? sm[t - off] : 0;
        __syncthreads();
        sm[t] += u;
        __syncthreads();
    }
    if (t < nb) bsum[t] = sm[t] - v;
    if (t == 255) ptr[n] = sm[255];
}

__global__ __launch_bounds__(256)
void scan_out_kernel(const int* __restrict__ cnt, const int* __restrict__ bsum,
                     int* __restrict__ ptr, int* __restrict__ pcur, int n)
{
    __shared__ int sm[256];
    const int t = threadIdx.x;
    const int i = blockIdx.x * 256 + t;
    const int v = (i < n) ? cnt[i] : 0;
    sm[t] = v;
    __syncthreads();
#pragma unroll
    for (int off = 1; off < 256; off <<= 1) {
        int u = (t >= off) ? sm[t - off] : 0;
        __syncthreads();
        sm[t] += u;
        __syncthreads();
    }
    if (i < n) {
        const int val = bsum[blockIdx.x] + sm[t] - v;
        ptr[i] = val;
        pcur[i] = val;
    }
}

__global__ __launch_bounds__(256)
void scatter_kernel(const int* __restrict__ ei, int* __restrict__ pcur,
                    int* __restrict__ esrc, int E)
{
    int e = blockIdx.x * 256 + threadIdx.x;
    if (e < E) {
        int dst = ei[E + e];
        int src = ei[e];
        int pos = atomicAdd(&pcur[dst], 1);
        esrc[pos] = src;
    }
}

// ---------------------------------------------------------------------------
extern "C" void kernel_launch(void* const* d_in, const int* in_sizes, int n_in,
                              void* d_out, int out_size, void* d_ws, size_t ws_size,
                              hipStream_t stream)
{
    const float* x       = (const float*)d_in[0];
    const int*   ei      = (const int*)d_in[1];
    const float* W0      = (const float*)d_in[2];
    const float* att_s0  = (const float*)d_in[3];
    const float* att_d0  = (const float*)d_in[4];
    const float* b0      = (const float*)d_in[5];
    const float* W1      = (const float*)d_in[6];
    const float* att_s1  = (const float*)d_in[7];
    const float* att_d1  = (const float*)d_in[8];
    const float* b1      = (const float*)d_in[9];
    const float* pw      = (const float*)d_in[10];
    const float* pb      = (const float*)d_in[11];

    const int N = in_sizes[0] / 256;   // 50000
    const int E = in_sizes[1] / 2;     // 800000
    const int NB = (N + 255) / 256;    // scan blocks (<=256)

    // workspace layout
    ushort* xlb  = (ushort*)d_ws;                    // N*256 fp16
    ushort* hbuf = xlb + (size_t)N * 256;            // N*128 fp16
    float*  a_s  = (float*)(hbuf + (size_t)N * 128); // N*2  (layer-0 scores)
    float*  a_d  = a_s + (size_t)N * 2;              // N*2
    float*  a_s2 = a_d + (size_t)N * 2;              // N*2  (layer-1 scores)
    float*  a_d2 = a_s2 + (size_t)N * 2;             // N*2
    float*  wtd0 = a_d2 + (size_t)N * 2;             // 256*4 (direct basis)
    float*  wt1  = wtd0 + 256 * 4;                   // 128*4
    int*    cnt  = (int*)(wt1 + 128 * 4);            // N
    int*    ptr  = cnt + N;                          // N+1
    int*    pcur = ptr + (N + 1);                    // N
    int*    bsm  = pcur + N;                         // 256
    int*    esr  = bsm + 256;                        // E
    ushort* w0h  = (ushort*)(esr + E);               // 256*256
    ushort* w0l  = w0h + 256 * 256;
    ushort* w1h  = w0l + 256 * 256;                  // 256*128
    ushort* w1l  = w1h + 256 * 128;
    ushort* pwh  = w1l + 256 * 128;                  // 128*128
    ushort* pwl  = pwh + 128 * 128;

    const int ablk = (N + 3) / 4;
    const int eblk = (E + 255) / 256;
    const int gblk = (N + 127) / 128;   // 391 GEMM row-blocks

    // ---- fused prep: splits + wt1 + wtd0 + cnt zeroing ----
    prep_kernel<<<577 + NB, 256, 0, stream>>>(
        W0, W1, pw, att_s0, att_d0, att_s1, att_d1,
        w0h, w0l, w1h, w1l, pwh, pwl, wtd0, wt1, cnt, N);

    // ---- CSR build ----
    hist_kernel<<<eblk, 256, 0, stream>>>(ei, cnt, E);
    blocksum_kernel<<<NB, 256, 0, stream>>>(cnt, bsm, N);
    scan_bsum_kernel<<<1, 256, 0, stream>>>(bsm, NB, ptr, N);
    scan_out_kernel<<<NB, 256, 0, stream>>>(cnt, bsm, ptr, pcur, N);
    scatter_kernel<<<eblk, 256, 0, stream>>>(ei, pcur, esr, E);

    // ---- layer 0 (GEMM epilogue also emits layer-0 scores, direct basis) --
    mfma_gemm3<256, true><<<gblk, 512, 0, stream>>>(
        x, nullptr, w0h, w0l, nullptr, nullptr, xlb, wtd0, a_s, a_d, N, 256);
    gat_gather_kernel<<<ablk, 256, 0, stream>>>(
        xlb, ptr, esr, a_s, a_d, b0, wt1, a_s2, a_d2, hbuf, N);

    // ---- layer 1 (A = hbuf fp16, exact) ----
    mfma_gemm3<256, false><<<gblk, 512, 0, stream>>>(
        nullptr, hbuf, w1h, w1l, nullptr, nullptr, xlb, nullptr, nullptr, nullptr, N, 128);
    gat_gather_kernel<<<ablk, 256, 0, stream>>>(
        xlb, ptr, esr, a_s2, a_d2, b1, nullptr, nullptr, nullptr, hbuf, N);

    // ---- projection ----
    mfma_gemm3<128, false><<<gblk, 512, 0, stream>>>(
        nullptr, hbuf, pwh, pwl, pb, (float*)d_out, nullptr, nullptr, nullptr, nullptr, N, 128);
}

// Round 17
// 326.582 us; speedup vs baseline: 1.0899x; 1.0181x over previous
//
#include <hip/hip_runtime.h>
#include <hip/hip_fp16.h>
#include <math.h>

// ---------------------------------------------------------------------------
// GATEncoder: 2x (GATConv(H=2,C=128) + exact GELU) + final projection.
// Carriers: fp16 (11-bit mantissa; all values bounded -> no range issues).
// GEMMs: 2-pass fp16 MFMA (A fp16 single, B split hi/lo -> B exact to 2^-22).
//        L1/proj A-operand (h) IS fp16 -> those GEMMs are ~fp32-exact.
//        BM=128 x BN=N tiles, 512 threads / 8 waves. A read once per layer.
//        L0 epilogue fuses the layer-0 attention matvec (output-basis table).
// Gather: DUAL-EDGE wave layout (lane=8ch x 16B; halves process edges j/j+1)
//        + fused no-max softmax + head-mean+bias+GELU+next-layer matvec.
//        Plateaued ~80us: bound by L2-miss->L3 service path (random 512B rows,
//        warm-cache replays equally slow; no swizzle fixes uniform-random).
// CSR: hist -> hierarchical Hillis-Steele scan -> scatter via pcur atomic.
// This round: restore of the round-14 best configuration (324.6 us).
// ---------------------------------------------------------------------------

#define NEG_SLOPE 0.2f

typedef __attribute__((ext_vector_type(8))) _Float16 f16x8;
typedef __attribute__((ext_vector_type(8))) ushort u16x8;
typedef __attribute__((ext_vector_type(4))) float f32x4;

__device__ __forceinline__ ushort f32_to_f16u(float x)
{
    return __half_as_ushort(__float2half(x));   // RNE
}

__device__ __forceinline__ float f16u_to_f32(ushort u)
{
    return __half2float(__ushort_as_half(u));
}

__device__ __forceinline__ void split_f16(float x, ushort& h, ushort& l)
{
    const __half hh = __float2half(x);
    h = __half_as_ushort(hh);
    l = __half_as_ushort(__float2half(x - __half2float(hh)));
}

__device__ __forceinline__ float lrelu(float x)
{
    return x > 0.f ? x : NEG_SLOPE * x;
}

__device__ __forceinline__ float gelu_exact(float x)
{
    return 0.5f * x * (1.0f + erff(x * 0.7071067811865476f));
}

// ---- fused prep: W splits + wt1 reduction + wtd0 direct + cnt zeroing -----
// blocks [0,448): split; [448,576): wt1 (W1@att1); 576: wtd0; [577,..): cnt=0
__global__ __launch_bounds__(256)
void prep_kernel(const float* __restrict__ W0, const float* __restrict__ W1,
                 const float* __restrict__ PW,
                 const float* __restrict__ as0, const float* __restrict__ ad0,
                 const float* __restrict__ as1, const float* __restrict__ ad1,
                 ushort* __restrict__ w0h, ushort* __restrict__ w0l,
                 ushort* __restrict__ w1h, ushort* __restrict__ w1l,
                 ushort* __restrict__ pwh, ushort* __restrict__ pwl,
                 float* __restrict__ wtd0, float* __restrict__ wt1,
                 int* __restrict__ cnt, int N)
{
    const int blk = blockIdx.x;
    if (blk >= 577) {
        int t2 = (blk - 577) * 256 + threadIdx.x;
        if (t2 < N) cnt[t2] = 0;
        return;
    }
    if (blk == 576) {
        // direct output-basis score table: score[v] = xl[v] . wtd0
        const int col = threadIdx.x;
        float4 o;
        if (col < 128) o = make_float4(as0[col], 0.f, ad0[col], 0.f);
        else           o = make_float4(0.f, as0[col], 0.f, ad0[col]);
        *(float4*)(wtd0 + col * 4) = o;
        return;
    }
    if (blk < 448) {
        int t = blk * 256 + threadIdx.x;
        ushort h, l;
        if (t < 65536) {                        // W0: [256][256] -> [N][K]
            int k = t >> 8, n = t & 255;
            split_f16(W0[t], h, l);
            w0h[n * 256 + k] = h; w0l[n * 256 + k] = l;
        } else if (t < 65536 + 32768) {         // W1: [128][256] -> [N][K=128]
            int u = t - 65536;
            int k = u >> 8, n = u & 255;
            split_f16(W1[u], h, l);
            w1h[n * 128 + k] = h; w1l[n * 128 + k] = l;
        } else {                                // PW: [128][128] -> [N][K]
            int u = t - 65536 - 32768;
            int k = u >> 7, n = u & 127;
            split_f16(PW[u], h, l);
            pwh[n * 128 + k] = h; pwl[n * 128 + k] = l;
        }
        return;
    }
    // wt1 path: wt1[k][4] = {W1@att_s1 h0,h1, W1@att_d1 h0,h1}, k in [0,128)
    const int k = blk - 448;
    const int t = threadIdx.x;
    const int h = t >> 7, c = t & 127;
    const int lane = t & 63, wid = t >> 6;
    const float w = W1[(size_t)k * 256 + h * 128 + c];
    float ps = w * as1[h * 128 + c];
    float pd = w * ad1[h * 128 + c];
#pragma unroll
    for (int off = 1; off < 64; off <<= 1) {
        ps += __shfl_xor(ps, off, 64);
        pd += __shfl_xor(pd, off, 64);
    }
    __shared__ float sm[4][2];
    if (lane == 0) { sm[wid][0] = ps; sm[wid][1] = pd; }
    __syncthreads();
    if (t == 0) {
        wt1[k * 4 + 0] = sm[0][0] + sm[1][0];
        wt1[k * 4 + 1] = sm[2][0] + sm[3][0];
        wt1[k * 4 + 2] = sm[0][1] + sm[1][1];
        wt1[k * 4 + 3] = sm[2][1] + sm[3][1];
    }
}

// ---------------- 2-pass fp16 MFMA GEMM: 8 waves, BM=128, BN=N -------------
template<int BN, bool SPLITA>
__global__ __launch_bounds__(512)
void mfma_gemm3(const float* __restrict__ Af,
                const ushort* __restrict__ A16,
                const ushort* __restrict__ Bth, const ushort* __restrict__ Btl,
                const float* __restrict__ bias,
                float* __restrict__ Cf, ushort* __restrict__ Cb,
                const float* __restrict__ watt,
                float* __restrict__ a_sc, float* __restrict__ a_dc,
                int M, int K)
{
    constexpr int NF = BN / 64;          // 16x16 col-frags per wave
    __shared__ ushort Ah[4][128][8];     // 8 KB
    __shared__ ushort Bh[4][BN][8];
    __shared__ ushort Bl[4][BN][8];

    const int tid = threadIdx.x;
    const int r0 = blockIdx.x * 128;
    const int w = tid >> 6, lane = tid & 63;
    const int wr = (w & 1) * 64;
    const int wc = (w >> 1) * (BN / 4);
    const int lr = lane & 15, kb = lane >> 4;

    const int arow = tid >> 2;           // 0..127
    const int apl = tid & 3;             // k-plane (8-wide)

    f32x4 acc[4][NF] = {};

    for (int kk = 0; kk < K; kk += 32) {
        // ---- stage A (128 x 32, fp16) ----
        {
            const int row = r0 + arow;
            u16x8 h0 = {};
            if (row < M) {
                if constexpr (SPLITA) {
                    const float* p = Af + (size_t)row * K + kk + apl * 8;
                    float4 v0 = *(const float4*)(p);
                    float4 v1 = *(const float4*)(p + 4);
                    h0[0] = f32_to_f16u(v0.x); h0[1] = f32_to_f16u(v0.y);
                    h0[2] = f32_to_f16u(v0.z); h0[3] = f32_to_f16u(v0.w);
                    h0[4] = f32_to_f16u(v1.x); h0[5] = f32_to_f16u(v1.y);
                    h0[6] = f32_to_f16u(v1.z); h0[7] = f32_to_f16u(v1.w);
                } else {
                    h0 = *(const u16x8*)(A16 + (size_t)row * K + kk + apl * 8);
                }
            }
            *(u16x8*)&Ah[apl][arow][0] = h0;
        }
        // ---- stage B (BN x 32) ----
        if constexpr (BN == 256) {
            const int col = tid >> 1, half = tid & 1;
            const ushort* ph = Bth + (size_t)col * K + kk + half * 16;
            const ushort* pl = Btl + (size_t)col * K + kk + half * 16;
            *(u16x8*)&Bh[half * 2 + 0][col][0] = *(const u16x8*)(ph);
            *(u16x8*)&Bh[half * 2 + 1][col][0] = *(const u16x8*)(ph + 8);
            *(u16x8*)&Bl[half * 2 + 0][col][0] = *(const u16x8*)(pl);
            *(u16x8*)&Bl[half * 2 + 1][col][0] = *(const u16x8*)(pl + 8);
        } else {
            const int col = tid >> 2, pl = tid & 3;
            *(u16x8*)&Bh[pl][col][0] = *(const u16x8*)(Bth + (size_t)col * K + kk + pl * 8);
            *(u16x8*)&Bl[pl][col][0] = *(const u16x8*)(Btl + (size_t)col * K + kk + pl * 8);
        }
        __syncthreads();

        f16x8 ah[4];
#pragma unroll
        for (int m = 0; m < 4; ++m)
            ah[m] = *(const f16x8*)&Ah[kb][wr + m * 16 + lr][0];
#pragma unroll
        for (int n = 0; n < NF; ++n) {
            const f16x8 bh = *(const f16x8*)&Bh[kb][wc + n * 16 + lr][0];
            const f16x8 bl = *(const f16x8*)&Bl[kb][wc + n * 16 + lr][0];
#pragma unroll
            for (int m = 0; m < 4; ++m) {
                acc[m][n] = __builtin_amdgcn_mfma_f32_16x16x32_f16(ah[m], bh, acc[m][n], 0, 0, 0);
                acc[m][n] = __builtin_amdgcn_mfma_f32_16x16x32_f16(ah[m], bl, acc[m][n], 0, 0, 0);
            }
        }
        __syncthreads();
    }

    // ---- C write ----
#pragma unroll
    for (int n = 0; n < NF; ++n) {
        const int col = wc + n * 16 + lr;
        const float bv = bias ? bias[col] : 0.f;
#pragma unroll
        for (int m = 0; m < 4; ++m) {
            const int rowb = r0 + wr + m * 16 + kb * 4;
#pragma unroll
            for (int j = 0; j < 4; ++j) {
                const int row = rowb + j;
                if (row < M) {
                    const float val = acc[m][n][j] + bv;
                    if (Cf) Cf[(size_t)row * BN + col] = val;
                    if (Cb) Cb[(size_t)row * BN + col] = f32_to_f16u(val);
                }
            }
        }
    }

    // ---- fused score matvec: a_s/a_d[row] = C_row . watt (output basis) ----
    if (watt) {
        float* sp = (float*)&Ah[0][0][0];   // 8 KB scratch, exact fit
        float4 wv[NF];
#pragma unroll
        for (int n = 0; n < NF; ++n)
            wv[n] = *(const float4*)(watt + (wc + n * 16 + lr) * 4);
#pragma unroll
        for (int m = 0; m < 4; ++m) {
#pragma unroll
            for (int j = 0; j < 4; ++j) {
                float s0 = 0.f, s1 = 0.f, s2 = 0.f, s3 = 0.f;
#pragma unroll
                for (int n = 0; n < NF; ++n) {
                    const float v = acc[m][n][j];
                    s0 += v * wv[n].x;
                    s1 += v * wv[n].y;
                    s2 += v * wv[n].z;
                    s3 += v * wv[n].w;
                }
#pragma unroll
                for (int off = 1; off < 16; off <<= 1) {
                    s0 += __shfl_xor(s0, off, 64);
                    s1 += __shfl_xor(s1, off, 64);
                    s2 += __shfl_xor(s2, off, 64);
                    s3 += __shfl_xor(s3, off, 64);
                }
                if (lr == 0) {
                    const int row = wr + m * 16 + kb * 4 + j;
                    float* d = sp + ((w >> 1) * 128 + row) * 4;
                    d[0] = s0; d[1] = s1; d[2] = s2; d[3] = s3;
                }
            }
        }
        __syncthreads();
        const int row = tid >> 2, comp = tid & 3;
        const float s = sp[(0 * 128 + row) * 4 + comp]
                      + sp[(1 * 128 + row) * 4 + comp]
                      + sp[(2 * 128 + row) * 4 + comp]
                      + sp[(3 * 128 + row) * 4 + comp];
        const int gr = r0 + row;
        if (gr < M) {
            if (comp < 2) a_sc[(size_t)gr * 2 + comp] = s;
            else          a_dc[(size_t)gr * 2 + (comp - 2)] = s;
        }
    }
}

// --------- fused gather: dual-edge layout + no-max softmax + epilogue ------
__global__ __launch_bounds__(256)
void gat_gather_kernel(const ushort* __restrict__ xlb,  // [n][256] fp16
                       const int* __restrict__ rowptr,
                       const int* __restrict__ esrc,
                       const float* __restrict__ a_si,
                       const float* __restrict__ a_di,
                       const float* __restrict__ bias,
                       const float* __restrict__ watt,  // nullable [128][4]
                       float* __restrict__ a_so, float* __restrict__ a_do,
                       ushort* __restrict__ outh,       // [n][128] fp16
                       int n)
{
    const int wave = threadIdx.x >> 6;
    const int lane = threadIdx.x & 63;
    const int v = blockIdx.x * 4 + wave;
    if (v >= n) return;
    const int half = lane >> 5;          // which edge of the pair
    const int il = lane & 31;            // channel-lane
    const int ch8 = il << 3;             // channels ch8..ch8+7
    const int hsel = il >> 4;            // head of my channel block

    const float2 advv = *(const float2*)(a_di + (size_t)v * 2);
    const float2 asvv = *(const float2*)(a_si + (size_t)v * 2);
    const float wself0 = __expf(lrelu(asvv.x + advv.x));
    const float wself1 = __expf(lrelu(asvv.y + advv.y));
    const float wselfh = hsel ? wself1 : wself0;

    const u16x8 xv = *(const u16x8*)(xlb + (size_t)v * 256 + ch8);
    float acc[8];
#pragma unroll
    for (int k = 0; k < 8; ++k)
        acc[k] = (half == 0) ? wselfh * f16u_to_f32(xv[k]) : 0.f;

    float ssum0 = (il == 0) ? wself0 : 0.f;   // per-half; halves replicate
    float ssum1 = (il == 0) ? wself1 : 0.f;

    const int beg = rowptr[v], end = rowptr[v + 1];
    for (int i = beg; i < end; i += 32) {
        const int cnt = min(32, end - i);
        int myidx = 0;
        float myw0 = 0.f, myw1 = 0.f;
        if (il < cnt) {
            myidx = esrc[i + il];
            const float2 e = *(const float2*)(a_si + (size_t)myidx * 2);
            myw0 = __expf(lrelu(e.x + advv.x));
            myw1 = __expf(lrelu(e.y + advv.y));
        }
        ssum0 += myw0;
        ssum1 += myw1;
#pragma unroll 2
        for (int j = 0; j < cnt; j += 2) {
            const int jj = j + half;                    // my half's edge
            const int src = __shfl(myidx, jj, 32);
            const float w0 = __shfl(myw0, jj, 32);
            const float w1 = __shfl(myw1, jj, 32);
            const float wgt = hsel ? w1 : w0;           // 0 when jj==cnt (odd tail)
            const u16x8 xs = *(const u16x8*)(xlb + (size_t)src * 256 + ch8);
#pragma unroll
            for (int k = 0; k < 8; ++k)
                acc[k] += wgt * f16u_to_f32(xs[k]);
        }
    }

    // denominators: reduce within each half (offsets <= 16 stay in-half)
#pragma unroll
    for (int off = 1; off <= 16; off <<= 1) {
        ssum0 += __shfl_xor(ssum0, off, 64);
        ssum1 += __shfl_xor(ssum1, off, 64);
    }
    const float inv = 1.0f / ((hsel ? ssum1 : ssum0) + 1e-16f);

    // combine the two edge-streams, normalize, head-mean (ch <-> ch+128)
    float o[8];
#pragma unroll
    for (int k = 0; k < 8; ++k) {
        float a = acc[k] + __shfl_xor(acc[k], 32, 64);
        a *= inv;
        o[k] = 0.5f * (a + __shfl_xor(a, 16, 64));
    }

    if (il < 16) {   // lanes holding final channels 0..127 (both halves)
        const float4 bb0 = *(const float4*)(bias + ch8);
        const float4 bb1 = *(const float4*)(bias + ch8 + 4);
        o[0] = gelu_exact(o[0] + bb0.x);
        o[1] = gelu_exact(o[1] + bb0.y);
        o[2] = gelu_exact(o[2] + bb0.z);
        o[3] = gelu_exact(o[3] + bb0.w);
        o[4] = gelu_exact(o[4] + bb1.x);
        o[5] = gelu_exact(o[5] + bb1.y);
        o[6] = gelu_exact(o[6] + bb1.z);
        o[7] = gelu_exact(o[7] + bb1.w);

        // fused next-layer attention matvec (channels counted once)
        if (watt) {
            float s0 = 0.f, s1 = 0.f, d0 = 0.f, d1 = 0.f;
#pragma unroll
            for (int k = 0; k < 8; ++k) {
                const float4 wv = *(const float4*)(watt + (ch8 + k) * 4);
                s0 += o[k] * wv.x;
                s1 += o[k] * wv.y;
                d0 += o[k] * wv.z;
                d1 += o[k] * wv.w;
            }
#pragma unroll
            for (int off = 1; off <= 8; off <<= 1) {
                s0 += __shfl_xor(s0, off, 64);
                s1 += __shfl_xor(s1, off, 64);
                d0 += __shfl_xor(d0, off, 64);
                d1 += __shfl_xor(d1, off, 64);
            }
            if (lane == 0) {
                *(float2*)(a_so + (size_t)v * 2) = make_float2(s0, s1);
                *(float2*)(a_do + (size_t)v * 2) = make_float2(d0, d1);
            }
        }

        // fp16 store: lanes 0..15 write the 128-wide row (256B per wave)
        if (half == 0) {
            u16x8 st;
#pragma unroll
            for (int k = 0; k < 8; ++k) st[k] = f32_to_f16u(o[k]);
            *(u16x8*)(outh + (size_t)v * 128 + ch8) = st;
        }
    }
}

// ---------------------- CSR build (by dst) ---------------------------------
__global__ __launch_bounds__(256)
void hist_kernel(const int* __restrict__ ei, int* __restrict__ cnt, int E)
{
    int e = blockIdx.x * 256 + threadIdx.x;
    if (e < E) atomicAdd(&cnt[ei[E + e]], 1);
}

__global__ __launch_bounds__(256)
void blocksum_kernel(const int* __restrict__ cnt, int* __restrict__ bsum, int n)
{
    __shared__ int sm[256];
    const int t = threadIdx.x;
    const int i = blockIdx.x * 256 + t;
    sm[t] = (i < n) ? cnt[i] : 0;
    __syncthreads();
#pragma unroll
    for (int off = 1; off < 256; off <<= 1) {
        int u = (t >= off) ? sm[t - off] : 0;
        __syncthreads();
        sm[t] += u;
        __syncthreads();
    }
    if (t == 255) bsum[blockIdx.x] = sm[255];
}

__global__ __launch_bounds__(256)
void scan_bsum_kernel(int* __restrict__ bsum, int nb, int* __restrict__ ptr, int n)
{
    __shared__ int sm[256];
    const int t = threadIdx.x;
    const int v = (t < nb) ? bsum[t] : 0;
    sm[t] = v;
    __syncthreads();
#pragma unroll
    for (int off = 1; off < 256; off <<= 1) {
        int u = (t >= off) ? sm[t - off] : 0;
        __syncthreads();
        sm[t] += u;
        __syncthreads();
    }
    if (t < nb) bsum[t] = sm[t] - v;
    if (t == 255) ptr[n] = sm[255];
}

__global__ __launch_bounds__(256)
void scan_out_kernel(const int* __restrict__ cnt, const int* __restrict__ bsum,
                     int* __restrict__ ptr, int* __restrict__ pcur, int n)
{
    __shared__ int sm[256];
    const int t = threadIdx.x;
    const int i = blockIdx.x * 256 + t;
    const int v = (i < n) ? cnt[i] : 0;
    sm[t] = v;
    __syncthreads();
#pragma unroll
    for (int off = 1; off < 256; off <<= 1) {
        int u = (t >= off) ? sm[t - off] : 0;
        __syncthreads();
        sm[t] += u;
        __syncthreads();
    }
    if (i < n) {
        const int val = bsum[blockIdx.x] + sm[t] - v;
        ptr[i] = val;
        pcur[i] = val;
    }
}

__global__ __launch_bounds__(256)
void scatter_kernel(const int* __restrict__ ei, int* __restrict__ pcur,
                    int* __restrict__ esrc, int E)
{
    int e = blockIdx.x * 256 + threadIdx.x;
    if (e < E) {
        int dst = ei[E + e];
        int src = ei[e];
        int pos = atomicAdd(&pcur[dst], 1);
        esrc[pos] = src;
    }
}

// ---------------------------------------------------------------------------
extern "C" void kernel_launch(void* const* d_in, const int* in_sizes, int n_in,
                              void* d_out, int out_size, void* d_ws, size_t ws_size,
                              hipStream_t stream)
{
    const float* x       = (const float*)d_in[0];
    const int*   ei      = (const int*)d_in[1];
    const float* W0      = (const float*)d_in[2];
    const float* att_s0  = (const float*)d_in[3];
    const float* att_d0  = (const float*)d_in[4];
    const float* b0      = (const float*)d_in[5];
    const float* W1      = (const float*)d_in[6];
    const float* att_s1  = (const float*)d_in[7];
    const float* att_d1  = (const float*)d_in[8];
    const float* b1      = (const float*)d_in[9];
    const float* pw      = (const float*)d_in[10];
    const float* pb      = (const float*)d_in[11];

    const int N = in_sizes[0] / 256;   // 50000
    const int E = in_sizes[1] / 2;     // 800000
    const int NB = (N + 255) / 256;    // scan blocks (<=256)

    // workspace layout
    ushort* xlb  = (ushort*)d_ws;                    // N*256 fp16
    ushort* hbuf = xlb + (size_t)N * 256;            // N*128 fp16
    float*  a_s  = (float*)(hbuf + (size_t)N * 128); // N*2  (layer-0 scores)
    float*  a_d  = a_s + (size_t)N * 2;              // N*2
    float*  a_s2 = a_d + (size_t)N * 2;              // N*2  (layer-1 scores)
    float*  a_d2 = a_s2 + (size_t)N * 2;             // N*2
    float*  wtd0 = a_d2 + (size_t)N * 2;             // 256*4 (direct basis)
    float*  wt1  = wtd0 + 256 * 4;                   // 128*4
    int*    cnt  = (int*)(wt1 + 128 * 4);            // N
    int*    ptr  = cnt + N;                          // N+1
    int*    pcur = ptr + (N + 1);                    // N
    int*    bsm  = pcur + N;                         // 256
    int*    esr  = bsm + 256;                        // E
    ushort* w0h  = (ushort*)(esr + E);               // 256*256
    ushort* w0l  = w0h + 256 * 256;
    ushort* w1h  = w0l + 256 * 256;                  // 256*128
    ushort* w1l  = w1h + 256 * 128;
    ushort* pwh  = w1l + 256 * 128;                  // 128*128
    ushort* pwl  = pwh + 128 * 128;

    const int ablk = (N + 3) / 4;
    const int eblk = (E + 255) / 256;
    const int gblk = (N + 127) / 128;   // 391 GEMM row-blocks

    // ---- fused prep: splits + wt1 + wtd0 + cnt zeroing ----
    prep_kernel<<<577 + NB, 256, 0, stream>>>(
        W0, W1, pw, att_s0, att_d0, att_s1, att_d1,
        w0h, w0l, w1h, w1l, pwh, pwl, wtd0, wt1, cnt, N);

    // ---- CSR build ----
    hist_kernel<<<eblk, 256, 0, stream>>>(ei, cnt, E);
    blocksum_kernel<<<NB, 256, 0, stream>>>(cnt, bsm, N);
    scan_bsum_kernel<<<1, 256, 0, stream>>>(bsm, NB, ptr, N);
    scan_out_kernel<<<NB, 256, 0, stream>>>(cnt, bsm, ptr, pcur, N);
    scatter_kernel<<<eblk, 256, 0, stream>>>(ei, pcur, esr, E);

    // ---- layer 0 (GEMM epilogue also emits layer-0 scores, direct basis) --
    mfma_gemm3<256, true><<<gblk, 512, 0, stream>>>(
        x, nullptr, w0h, w0l, nullptr, nullptr, xlb, wtd0, a_s, a_d, N, 256);
    gat_gather_kernel<<<ablk, 256, 0, stream>>>(
        xlb, ptr, esr, a_s, a_d, b0, wt1, a_s2, a_d2, hbuf, N);

    // ---- layer 1 (A = hbuf fp16, exact) ----
    mfma_gemm3<256, false><<<gblk, 512, 0, stream>>>(
        nullptr, hbuf, w1h, w1l, nullptr, nullptr, xlb, nullptr, nullptr, nullptr, N, 128);
    gat_gather_kernel<<<ablk, 256, 0, stream>>>(
        xlb, ptr, esr, a_s2, a_d2, b1, nullptr, nullptr, nullptr, hbuf, N);

    // ---- projection ----
    mfma_gemm3<128, false><<<gblk, 512, 0, stream>>>(
        nullptr, hbuf, pwh, pwl, pb, (float*)d_out, nullptr, nullptr, nullptr, nullptr, N, 128);
}